// Round 4
// baseline (192.595 us; speedup 1.0000x reference)
//
#include <hip/hip_runtime.h>

// Problem constants (from setup_inputs)
#define B_     2
#define NPB    8192      // N per batch
#define NQ     16384     // B*N
#define M2     8192
#define M3     4096
#define M4     2048
#define SEG    1024      // known-points per segment job
#define NLS    14        // 8 + 4 + 2 segment-jobs per query
#define NQT    256       // query tiles of 64 lanes
#define NJOBS  (NQT*NLS) // 3584 waves

// Referee model (jax): d = (su - 2*p) + sk, left-to-right, fp32.
// su/sk: elementwise square + sequential reduce, NO FMA.
// p: K=3 GEMM (Eigen/rocBLAS), ascending-k FMA chain: fma(u2,k2,fma(u1,k1,u0*k0)).
__device__ __forceinline__ float np_sqnorm(float x, float y, float z) {
    return __fadd_rn(__fadd_rn(__fmul_rn(x, x), __fmul_rn(y, y)), __fmul_rn(z, z));
}
__device__ __forceinline__ float gemm_dot3(float ux, float uy, float uz,
                                           float kx, float ky, float kz) {
    return fmaf(uz, kz, fmaf(uy, ky, __fmul_rn(ux, kx)));
}
__device__ __forceinline__ float ref_dist(float su, float p, float sk) {
    return __fadd_rn(__fsub_rn(su, __fmul_rn(2.0f, p)), sk);
}

// ---------------------------------------------------------------- kernel 1
// wc = w_fc @ w_cls fold; S_u for all queries; S_k for all known points.
__global__ void k_prep_v4(const float* __restrict__ w_fc, const float* __restrict__ w_cls,
                          const float* __restrict__ pts,
                          const float* __restrict__ xyz2, const float* __restrict__ xyz3,
                          const float* __restrict__ xyz4,
                          float* __restrict__ wc, float* __restrict__ su,
                          float* __restrict__ sk2, float* __restrict__ sk3,
                          float* __restrict__ sk4) {
    int i = blockIdx.x * 256 + threadIdx.x;
    if (i < 320) {
        float acc = 0.f;
#pragma unroll
        for (int j = 0; j < 64; ++j) acc = fmaf(w_fc[i * 64 + j], w_cls[j], acc);
        wc[i] = acc;
        return;
    }
    int j = i - 320;
    if (j < NQ)        { const float* p = pts  + (size_t)j * 3; su[j]  = np_sqnorm(p[0], p[1], p[2]); return; }
    j -= NQ;
    if (j < B_ * M2)   { const float* p = xyz2 + (size_t)j * 3; sk2[j] = np_sqnorm(p[0], p[1], p[2]); return; }
    j -= B_ * M2;
    if (j < B_ * M3)   { const float* p = xyz3 + (size_t)j * 3; sk3[j] = np_sqnorm(p[0], p[1], p[2]); return; }
    j -= B_ * M3;
    if (j < B_ * M4)   { const float* p = xyz4 + (size_t)j * 3; sk4[j] = np_sqnorm(p[0], p[1], p[2]); return; }
}

// ---------------------------------------------------------------- kernel 2
// g_lvl[b,m] = feat_lvl[b,m,:] . wc_slice   (one wave per known point)
__global__ void k_gdot_v4(const float* __restrict__ f2, const float* __restrict__ f3,
                          const float* __restrict__ f4, const float* __restrict__ wc,
                          float* __restrict__ g2, float* __restrict__ g3,
                          float* __restrict__ g4) {
    int gid  = blockIdx.x * blockDim.x + threadIdx.x;
    int w    = gid >> 6;
    int lane = gid & 63;
    float v;
    if (w < 16384) {                         // level2: C=64, wc[0:64)
        v = f2[(size_t)w * 64 + lane] * wc[lane];
    } else if (w < 24576) {                  // level3: C=128, wc[64:192)
        size_t base = (size_t)(w - 16384) * 128;
        v = fmaf(f3[base + 64 + lane], wc[128 + lane], f3[base + lane] * wc[64 + lane]);
    } else {                                 // level4: C=128, wc[192:320)
        size_t base = (size_t)(w - 24576) * 128;
        v = fmaf(f4[base + 64 + lane], wc[256 + lane], f4[base + lane] * wc[192 + lane]);
    }
    for (int off = 32; off; off >>= 1) v += __shfl_down(v, off, 64);
    if (lane == 0) {
        if (w < 16384) g2[w] = v;
        else if (w < 24576) g3[w - 16384] = v;
        else g4[w - 24576] = v;
    }
}

// ---------------------------------------------------------------- kernel 3
// Brute-force scan on the referee-model distance (expansion + FMA-chain p).
// Each wave = 64 queries x one 1024-point segment; keeps top-4 (stable).
__launch_bounds__(256, 4)
__global__ void k_scan_v4(const float* __restrict__ pts,
                          const float* __restrict__ xyz2, const float* __restrict__ xyz3,
                          const float* __restrict__ xyz4,
                          const float* __restrict__ su,
                          const float* __restrict__ sk2, const float* __restrict__ sk3,
                          const float* __restrict__ sk4,
                          int* __restrict__ nidx) {
    int tid  = blockIdx.x * 256 + threadIdx.x;
    int job  = __builtin_amdgcn_readfirstlane(tid >> 6);   // wave-uniform -> SGPR
    int lane = threadIdx.x & 63;

    int qtile = job / NLS;          // scalar
    int ls    = job - qtile * NLS;  // scalar: 0..13
    int b     = qtile >> 7;         // 128 qtiles per batch -> scalar
    int q     = (qtile << 6) + lane;

    float ux = pts[q * 3 + 0], uy = pts[q * 3 + 1], uz = pts[q * 3 + 2];
    float suq = su[q];

    const float* kp; const float* skp; int mbase;
    if (ls < 8)       { mbase = ls << 10;        kp = xyz2 + ((size_t)b * M2 + mbase) * 3; skp = sk2 + b * M2 + mbase; }
    else if (ls < 12) { mbase = (ls - 8) << 10;  kp = xyz3 + ((size_t)b * M3 + mbase) * 3; skp = sk3 + b * M3 + mbase; }
    else              { mbase = (ls - 12) << 10; kp = xyz4 + ((size_t)b * M4 + mbase) * 3; skp = sk4 + b * M4 + mbase; }

    float d0 = 3e38f, d1 = 3e38f, d2 = 3e38f, d3 = 3e38f;
    int   i0 = mbase, i1 = mbase, i2 = mbase, i3 = mbase;

#pragma unroll 4
    for (int t = 0; t < SEG; ++t) {
        float kx = kp[3 * t], ky = kp[3 * t + 1], kz = kp[3 * t + 2]; // uniform -> s_load
        float p  = gemm_dot3(ux, uy, uz, kx, ky, kz);
        float d  = ref_dist(suq, p, skp[t]);
        if (d < d3) {                    // strict < keeps lowest index on ties
            if (d < d2) {
                d3 = d2; i3 = i2;
                if (d < d1) {
                    d2 = d1; i2 = i1;
                    if (d < d0) { d1 = d0; i1 = i0; d0 = d; i0 = mbase + t; }
                    else        { d1 = d;  i1 = mbase + t; }
                } else { d2 = d; i2 = mbase + t; }
            } else { d3 = d; i3 = mbase + t; }
        }
    }
    int base = job * 256 + lane;         // [job][k][lane] -> coalesced
    nidx[base]       = i0;
    nidx[base + 64]  = i1;
    nidx[base + 128] = i2;
    nidx[base + 192] = i3;
}

// ---------------------------------------------------------------- kernel 4
// Merge: re-rank the 56 candidates on the SAME referee-model distance,
// select top-3 per level (tie -> lowest index), bit-exact fp32 weights,
// f64 fold of the weighted g-sum.
__global__ void k_merge_v4(const float* __restrict__ pts,
                           const float* __restrict__ xyz2, const float* __restrict__ xyz3,
                           const float* __restrict__ xyz4,
                           const float* __restrict__ su,
                           const float* __restrict__ sk2, const float* __restrict__ sk3,
                           const float* __restrict__ sk4,
                           const float* __restrict__ g2, const float* __restrict__ g3,
                           const float* __restrict__ g4,
                           const int* __restrict__ nidx, float* __restrict__ out) {
    int q = blockIdx.x * 256 + threadIdx.x;
    if (q >= NQ) return;
    int qtile = q >> 6, lane = q & 63;
    int b = q >> 13;

    float ux = pts[q * 3 + 0], uy = pts[q * 3 + 1], uz = pts[q * 3 + 2];
    float suq = su[q];
    double acc = 0.0;

    for (int lvl = 0; lvl < 3; ++lvl) {
        const float* xyz; const float* sk; const float* g; int ls0, nls;
        if (lvl == 0)      { xyz = xyz2 + (size_t)b * M2 * 3; sk = sk2 + b * M2; g = g2 + b * M2; ls0 = 0;  nls = 8; }
        else if (lvl == 1) { xyz = xyz3 + (size_t)b * M3 * 3; sk = sk3 + b * M3; g = g3 + b * M3; ls0 = 8;  nls = 4; }
        else               { xyz = xyz4 + (size_t)b * M4 * 3; sk = sk4 + b * M4; g = g4 + b * M4; ls0 = 12; nls = 2; }

        float d0 = 3e38f, d1 = 3e38f, d2 = 3e38f;
        int   i0 = 0, i1 = 0, i2 = 0;
        // encounter order = (segment asc, rank asc) == ascending index among
        // equal-d candidates; strict < therefore matches stable top-k ties.
        for (int s = 0; s < nls; ++s) {
            int jb = ((qtile * NLS) + ls0 + s) * 256 + lane;
#pragma unroll
            for (int k = 0; k < 4; ++k) {
                int idx = nidx[jb + k * 64];
                float p = gemm_dot3(ux, uy, uz,
                                    xyz[idx * 3 + 0], xyz[idx * 3 + 1], xyz[idx * 3 + 2]);
                float d = ref_dist(suq, p, sk[idx]);
                if (d < d2) {
                    if (d < d1) {
                        d2 = d1; i2 = i1;
                        if (d < d0) { d1 = d0; i1 = i0; d0 = d; i0 = idx; }
                        else        { d1 = d;  i1 = idx; }
                    } else { d2 = d; i2 = idx; }
                }
            }
        }
        // referee weights, bit-exact fp32: r=1/(d+1e-8); w=r/((r0+r1)+r2)
        float r0 = __fdiv_rn(1.0f, __fadd_rn(d0, 1e-8f));
        float r1 = __fdiv_rn(1.0f, __fadd_rn(d1, 1e-8f));
        float r2 = __fdiv_rn(1.0f, __fadd_rn(d2, 1e-8f));
        float s  = __fadd_rn(__fadd_rn(r0, r1), r2);
        float w0 = __fdiv_rn(r0, s), w1 = __fdiv_rn(r1, s), w2 = __fdiv_rn(r2, s);
        acc += (double)w0 * (double)g[i0] + (double)w1 * (double)g[i1]
             + (double)w2 * (double)g[i2];
    }
    out[q] = (float)acc;
}

// ---------------------------------------------------------------- launch
extern "C" void kernel_launch(void* const* d_in, const int* in_sizes, int n_in,
                              void* d_out, int out_size, void* d_ws, size_t ws_size,
                              hipStream_t stream) {
    const float* pts   = (const float*)d_in[0];
    const float* xyz2  = (const float*)d_in[1];
    const float* feat2 = (const float*)d_in[2];
    const float* xyz3  = (const float*)d_in[3];
    const float* feat3 = (const float*)d_in[4];
    const float* xyz4  = (const float*)d_in[5];
    const float* feat4 = (const float*)d_in[6];
    const float* w_fc  = (const float*)d_in[7];
    const float* w_cls = (const float*)d_in[8];
    float* out = (float*)d_out;

    // workspace layout (floats then ints), ~4.0 MB total
    float* wc  = (float*)d_ws;           // 320
    float* g2  = wc + 320;               // 16384
    float* g3  = g2 + 16384;             // 8192
    float* g4  = g3 + 8192;              // 4096
    float* su  = g4 + 4096;              // 16384
    float* sk2 = su + 16384;             // 16384
    float* sk3 = sk2 + 16384;            // 8192
    float* sk4 = sk3 + 8192;             // 4096
    int*   ni  = (int*)(sk4 + 4096);     // NJOBS*256 = 917504 ints

    int prep_threads = 320 + NQ + B_ * M2 + B_ * M3 + B_ * M4;  // 45376
    k_prep_v4<<<(prep_threads + 255) / 256, 256, 0, stream>>>(
        w_fc, w_cls, pts, xyz2, xyz3, xyz4, wc, su, sk2, sk3, sk4);
    k_gdot_v4<<<7168, 256, 0, stream>>>(feat2, feat3, feat4, wc, g2, g3, g4);
    k_scan_v4<<<NJOBS / 4, 256, 0, stream>>>(pts, xyz2, xyz3, xyz4, su, sk2, sk3, sk4, ni);
    k_merge_v4<<<NQ / 256, 256, 0, stream>>>(pts, xyz2, xyz3, xyz4, su, sk2, sk3, sk4,
                                             g2, g3, g4, ni, out);
}

// Round 5
// 144.853 us; speedup vs baseline: 1.3296x; 1.3296x over previous
//
#include <hip/hip_runtime.h>

// Problem constants (from setup_inputs)
#define B_     2
#define NPB    8192      // N per batch
#define NQ     16384     // B*N
#define M2     8192
#define M3     4096
#define M4     2048
#define SEG    512       // known-points per segment job
#define NLS    28        // 16 + 8 + 4 segment-jobs per query
#define NQT    256       // query tiles of 64 lanes
#define NJOBS  (NQT*NLS) // 7168 waves

// Referee model (jax/XLA, verified R4): d = (su - 2*p) + sk, left-to-right fp32.
// su/sk: elementwise square + sequential reduce, NO FMA.
// p: K=3 GEMM ascending-k FMA chain: fma(u2,k2,fma(u1,k1,u0*k0)).
// Note fl(2p) is exact (pow2 scale), so fmaf(-2,p,su) == fsub(su, fmul(2,p)).
__device__ __forceinline__ float np_sqnorm(float x, float y, float z) {
    return __fadd_rn(__fadd_rn(__fmul_rn(x, x), __fmul_rn(y, y)), __fmul_rn(z, z));
}
__device__ __forceinline__ float ref_dist(float su, float ux, float uy, float uz,
                                          float kx, float ky, float kz, float sk) {
    float p = fmaf(uz, kz, fmaf(uy, ky, __fmul_rn(ux, kx)));
    return __fadd_rn(fmaf(-2.0f, p, su), sk);
}

// ---------------------------------------------------------------- kernel 1
// wc = w_fc @ w_cls fold; su for all queries; packed [kx,ky,kz,sk] per known pt.
__global__ void k_prep_v5(const float* __restrict__ w_fc, const float* __restrict__ w_cls,
                          const float* __restrict__ pts,
                          const float* __restrict__ xyz2, const float* __restrict__ xyz3,
                          const float* __restrict__ xyz4,
                          float* __restrict__ wc, float* __restrict__ su,
                          float4* __restrict__ pk2, float4* __restrict__ pk3,
                          float4* __restrict__ pk4) {
    int i = blockIdx.x * 256 + threadIdx.x;
    if (i < 320) {
        float acc = 0.f;
#pragma unroll
        for (int j = 0; j < 64; ++j) acc = fmaf(w_fc[i * 64 + j], w_cls[j], acc);
        wc[i] = acc;
        return;
    }
    int j = i - 320;
    if (j < NQ) {
        const float* p = pts + (size_t)j * 3;
        su[j] = np_sqnorm(p[0], p[1], p[2]);
        return;
    }
    j -= NQ;
    if (j < B_ * M2) {
        const float* p = xyz2 + (size_t)j * 3;
        pk2[j] = make_float4(p[0], p[1], p[2], np_sqnorm(p[0], p[1], p[2]));
        return;
    }
    j -= B_ * M2;
    if (j < B_ * M3) {
        const float* p = xyz3 + (size_t)j * 3;
        pk3[j] = make_float4(p[0], p[1], p[2], np_sqnorm(p[0], p[1], p[2]));
        return;
    }
    j -= B_ * M3;
    if (j < B_ * M4) {
        const float* p = xyz4 + (size_t)j * 3;
        pk4[j] = make_float4(p[0], p[1], p[2], np_sqnorm(p[0], p[1], p[2]));
        return;
    }
}

// ---------------------------------------------------------------- kernel 2
// g_lvl[b,m] = feat_lvl[b,m,:] . wc_slice   (one wave per known point)
__global__ void k_gdot_v5(const float* __restrict__ f2, const float* __restrict__ f3,
                          const float* __restrict__ f4, const float* __restrict__ wc,
                          float* __restrict__ g2, float* __restrict__ g3,
                          float* __restrict__ g4) {
    int gid  = blockIdx.x * blockDim.x + threadIdx.x;
    int w    = gid >> 6;
    int lane = gid & 63;
    float v;
    if (w < 16384) {                         // level2: C=64, wc[0:64)
        v = f2[(size_t)w * 64 + lane] * wc[lane];
    } else if (w < 24576) {                  // level3: C=128, wc[64:192)
        size_t base = (size_t)(w - 16384) * 128;
        v = fmaf(f3[base + 64 + lane], wc[128 + lane], f3[base + lane] * wc[64 + lane]);
    } else {                                 // level4: C=128, wc[192:320)
        size_t base = (size_t)(w - 24576) * 128;
        v = fmaf(f4[base + 64 + lane], wc[256 + lane], f4[base + lane] * wc[192 + lane]);
    }
    for (int off = 32; off; off >>= 1) v += __shfl_down(v, off, 64);
    if (lane == 0) {
        if (w < 16384) g2[w] = v;
        else if (w < 24576) g3[w - 16384] = v;
        else g4[w - 24576] = v;
    }
}

// ---------------------------------------------------------------- kernel 3
// Brute-force scan, branchless med3 top-3 on the exact referee distance.
// Each wave = 64 queries x one 512-point segment. Stores (d, idx) pairs.
__launch_bounds__(256, 4)
__global__ void k_scan_v5(const float* __restrict__ pts,
                          const float4* __restrict__ pk2, const float4* __restrict__ pk3,
                          const float4* __restrict__ pk4,
                          const float* __restrict__ su,
                          float* __restrict__ nd, int* __restrict__ ni) {
    int tid  = blockIdx.x * 256 + threadIdx.x;
    int job  = __builtin_amdgcn_readfirstlane(tid >> 6);   // wave-uniform -> SGPR
    int lane = threadIdx.x & 63;

    int qtile = job / NLS;          // scalar (magic-mul)
    int ls    = job - qtile * NLS;  // scalar: 0..27
    int b     = qtile >> 7;         // 128 qtiles per batch -> scalar
    int q     = (qtile << 6) + lane;

    float ux = pts[q * 3 + 0], uy = pts[q * 3 + 1], uz = pts[q * 3 + 2];
    float suq = su[q];

    const float4* kp; int mbase;
    if (ls < 16)      { mbase = ls << 9;         kp = pk2 + (size_t)b * M2 + mbase; }
    else if (ls < 24) { mbase = (ls - 16) << 9;  kp = pk3 + (size_t)b * M3 + mbase; }
    else              { mbase = (ls - 24) << 9;  kp = pk4 + (size_t)b * M4 + mbase; }

    float d0 = 3e38f, d1 = 3e38f, d2 = 3e38f;
    int   i0 = mbase, i1 = mbase, i2 = mbase;

#pragma unroll 4
    for (int t = 0; t < SEG; ++t) {
        float4 kv = kp[t];                                  // uniform -> s_load_dwordx4
        float d = ref_dist(suq, ux, uy, uz, kv.x, kv.y, kv.z, kv.w);
        int   ti = mbase + t;                               // uniform value
        // strict < keeps lowest index on exact ties (stable top-k semantics)
        bool c0 = d < d0, c1 = d < d1, c2 = d < d2;
        int ni0 = c0 ? ti : i0;
        int ni1 = c1 ? (c0 ? i0 : ti) : i1;
        int ni2 = c2 ? (c1 ? i1 : ti) : i2;
        float nd1 = __builtin_amdgcn_fmed3f(d, d0, d1);     // sorted-insert slot1
        float nd2 = __builtin_amdgcn_fmed3f(d, d1, d2);     // sorted-insert slot2
        d0 = fminf(d, d0); d1 = nd1; d2 = nd2;
        i0 = ni0; i1 = ni1; i2 = ni2;
    }
    int base = job * 192 + lane;         // [job][k][lane] -> coalesced
    nd[base]       = d0;  ni[base]       = i0;
    nd[base + 64]  = d1;  ni[base + 64]  = i1;
    nd[base + 128] = d2;  ni[base + 128] = i2;
}

// ---------------------------------------------------------------- kernel 4
// Merge: rank stored exact (d,idx) pairs per level (segments ascending ->
// stable ties to lowest index), bit-exact fp32 weights, f64 g-fold.
__global__ void k_merge_v5(const float* __restrict__ nd, const int* __restrict__ ni,
                           const float* __restrict__ g2, const float* __restrict__ g3,
                           const float* __restrict__ g4,
                           float* __restrict__ out) {
    int q = blockIdx.x * 256 + threadIdx.x;
    if (q >= NQ) return;
    int qtile = q >> 6, lane = q & 63;
    int b = q >> 13;

    double acc = 0.0;
    for (int lvl = 0; lvl < 3; ++lvl) {
        const float* g; int ls0, nseg;
        if (lvl == 0)      { g = g2 + b * M2; ls0 = 0;  nseg = 16; }
        else if (lvl == 1) { g = g3 + b * M3; ls0 = 16; nseg = 8;  }
        else               { g = g4 + b * M4; ls0 = 24; nseg = 4;  }

        float d0 = 3e38f, d1 = 3e38f, d2 = 3e38f;
        int   i0 = 0, i1 = 0, i2 = 0;
        for (int s = 0; s < nseg; ++s) {
            int jb = ((qtile * NLS) + ls0 + s) * 192 + lane;
#pragma unroll
            for (int k = 0; k < 3; ++k) {
                float d = nd[jb + k * 64];
                int idx = ni[jb + k * 64];
                if (d < d2) {
                    if (d < d1) {
                        d2 = d1; i2 = i1;
                        if (d < d0) { d1 = d0; i1 = i0; d0 = d; i0 = idx; }
                        else        { d1 = d;  i1 = idx; }
                    } else { d2 = d; i2 = idx; }
                }
            }
        }
        // referee weights, bit-exact fp32: r=1/(d+1e-8); w=r/((r0+r1)+r2)
        float r0 = __fdiv_rn(1.0f, __fadd_rn(d0, 1e-8f));
        float r1 = __fdiv_rn(1.0f, __fadd_rn(d1, 1e-8f));
        float r2 = __fdiv_rn(1.0f, __fadd_rn(d2, 1e-8f));
        float s  = __fadd_rn(__fadd_rn(r0, r1), r2);
        float w0 = __fdiv_rn(r0, s), w1 = __fdiv_rn(r1, s), w2 = __fdiv_rn(r2, s);
        acc += (double)w0 * (double)g[i0] + (double)w1 * (double)g[i1]
             + (double)w2 * (double)g[i2];
    }
    out[q] = (float)acc;
}

// ---------------------------------------------------------------- launch
extern "C" void kernel_launch(void* const* d_in, const int* in_sizes, int n_in,
                              void* d_out, int out_size, void* d_ws, size_t ws_size,
                              hipStream_t stream) {
    const float* pts   = (const float*)d_in[0];
    const float* xyz2  = (const float*)d_in[1];
    const float* feat2 = (const float*)d_in[2];
    const float* xyz3  = (const float*)d_in[3];
    const float* feat3 = (const float*)d_in[4];
    const float* xyz4  = (const float*)d_in[5];
    const float* feat4 = (const float*)d_in[6];
    const float* w_fc  = (const float*)d_in[7];
    const float* w_cls = (const float*)d_in[8];
    float* out = (float*)d_out;

    // workspace layout, ~11.2 MB total
    float*  wc  = (float*)d_ws;            // 320
    float*  g2  = wc + 320;                // 16384
    float*  g3  = g2 + 16384;              // 8192
    float*  g4  = g3 + 8192;               // 4096
    float*  su  = g4 + 4096;               // 16384  (float offset 45376 -> 16B aligned)
    float4* pk2 = (float4*)(su + 16384);   // 16384 float4
    float4* pk3 = pk2 + B_ * M2;           // 8192 float4
    float4* pk4 = pk3 + B_ * M3;           // 4096 float4
    float*  nd  = (float*)(pk4 + B_ * M4); // NJOBS*192 = 1376256 floats
    int*    ni  = (int*)(nd + NJOBS * 192);// 1376256 ints

    int prep_threads = 320 + NQ + B_ * (M2 + M3 + M4);  // 45376
    k_prep_v5<<<(prep_threads + 255) / 256, 256, 0, stream>>>(
        w_fc, w_cls, pts, xyz2, xyz3, xyz4, wc, su, pk2, pk3, pk4);
    k_gdot_v5<<<7168, 256, 0, stream>>>(feat2, feat3, feat4, wc, g2, g3, g4);
    k_scan_v5<<<NJOBS / 4, 256, 0, stream>>>(pts, pk2, pk3, pk4, su, nd, ni);
    k_merge_v5<<<NQ / 256, 256, 0, stream>>>(nd, ni, g2, g3, g4, out);
}

// Round 6
// 120.502 us; speedup vs baseline: 1.5983x; 1.2021x over previous
//
#include <hip/hip_runtime.h>

// Problem constants (from setup_inputs)
#define B_     2
#define NQ     16384     // B*N
#define M2     8192
#define M3     4096
#define M4     2048
#define SEG    512       // known-points per segment job
#define NLS    28        // 16 + 8 + 4 segment-jobs per query
#define NQT    256       // query tiles of 64 lanes
#define NJOBS  (NQT*NLS) // 7168 waves

#define GDOT_BLOCKS 7168                       // 28672 waves, one per known point
#define PREP_THREADS (320 + NQ + B_*(M2+M3+M4)) // 45376
#define PREP_BLOCKS 178
#define FRONT_BLOCKS (GDOT_BLOCKS + PREP_BLOCKS)

// Referee model (jax/XLA, verified R4): d = (su - 2*p) + sk, left-to-right fp32.
// su/sk: elementwise square + sequential reduce, NO FMA.
// p: K=3 GEMM ascending-k FMA chain: fma(u2,k2,fma(u1,k1,u0*k0)).
// fl(2p) is exact (pow2 scale), so fmaf(-2,p,su) == fsub(su, fmul(2,p)).
__device__ __forceinline__ float np_sqnorm(float x, float y, float z) {
    return __fadd_rn(__fadd_rn(__fmul_rn(x, x), __fmul_rn(y, y)), __fmul_rn(z, z));
}
__device__ __forceinline__ float ref_dist(float su, float ux, float uy, float uz,
                                          float kx, float ky, float kz, float sk) {
    float p = fmaf(uz, kz, fmaf(uy, ky, __fmul_rn(ux, kx)));
    return __fadd_rn(fmaf(-2.0f, p, su), sk);
}

// ---------------------------------------------------------------- kernel 1
// Fused front: gdot (blocks [0,7168)) + prep (blocks [7168,7346)).
__global__ void k_front_v6(const float* __restrict__ w_fc, const float* __restrict__ w_cls,
                           const float* __restrict__ pts,
                           const float* __restrict__ xyz2, const float* __restrict__ xyz3,
                           const float* __restrict__ xyz4,
                           const float* __restrict__ f2, const float* __restrict__ f3,
                           const float* __restrict__ f4,
                           float* __restrict__ wc, float* __restrict__ su,
                           float4* __restrict__ pk2, float4* __restrict__ pk3,
                           float4* __restrict__ pk4,
                           float* __restrict__ g2, float* __restrict__ g3,
                           float* __restrict__ g4) {
    if (blockIdx.x < GDOT_BLOCKS) {
        // g_lvl[b,m] = feat_lvl[b,m,:] . wc_slice  (one wave per known point)
        int gid  = blockIdx.x * 256 + threadIdx.x;
        int w    = gid >> 6;
        int lane = gid & 63;
        float v;
        if (w < 16384) {                         // level2: C=64, wc[0:64)
            v = f2[(size_t)w * 64 + lane] * wc[lane];
        } else if (w < 24576) {                  // level3: C=128, wc[64:192)
            size_t base = (size_t)(w - 16384) * 128;
            v = fmaf(f3[base + 64 + lane], wc[128 + lane], f3[base + lane] * wc[64 + lane]);
        } else {                                 // level4: C=128, wc[192:320)
            size_t base = (size_t)(w - 24576) * 128;
            v = fmaf(f4[base + 64 + lane], wc[256 + lane], f4[base + lane] * wc[192 + lane]);
        }
        for (int off = 32; off; off >>= 1) v += __shfl_down(v, off, 64);
        if (lane == 0) {
            if (w < 16384) g2[w] = v;
            else if (w < 24576) g3[w - 16384] = v;
            else g4[w - 24576] = v;
        }
        return;
    }
    // prep role
    int i = (blockIdx.x - GDOT_BLOCKS) * 256 + threadIdx.x;
    if (i < 320) {
        float acc = 0.f;
#pragma unroll
        for (int j = 0; j < 64; ++j) acc = fmaf(w_fc[i * 64 + j], w_cls[j], acc);
        wc[i] = acc;   // NOTE: gdot reads wc from a PREVIOUS launch? No -- see below.
        return;
    }
    int j = i - 320;
    if (j < NQ) {
        const float* p = pts + (size_t)j * 3;
        su[j] = np_sqnorm(p[0], p[1], p[2]);
        return;
    }
    j -= NQ;
    if (j < B_ * M2) {
        const float* p = xyz2 + (size_t)j * 3;
        pk2[j] = make_float4(p[0], p[1], p[2], np_sqnorm(p[0], p[1], p[2]));
        return;
    }
    j -= B_ * M2;
    if (j < B_ * M3) {
        const float* p = xyz3 + (size_t)j * 3;
        pk3[j] = make_float4(p[0], p[1], p[2], np_sqnorm(p[0], p[1], p[2]));
        return;
    }
    j -= B_ * M3;
    if (j < B_ * M4) {
        const float* p = xyz4 + (size_t)j * 3;
        pk4[j] = make_float4(p[0], p[1], p[2], np_sqnorm(p[0], p[1], p[2]));
        return;
    }
}

// wc must be ready before gdot blocks run; no intra-kernel ordering exists, so
// wc is computed by its own tiny kernel BEFORE k_front (2 blocks, ~1us).
__global__ void k_wc_v6(const float* __restrict__ w_fc, const float* __restrict__ w_cls,
                        float* __restrict__ wc) {
    int c = blockIdx.x * 256 + threadIdx.x;
    if (c < 320) {
        float acc = 0.f;
#pragma unroll
        for (int j = 0; j < 64; ++j) acc = fmaf(w_fc[c * 64 + j], w_cls[j], acc);
        wc[c] = acc;
    }
}

// ---------------------------------------------------------------- kernel 2
// Brute-force scan on exact referee distance; 8-deep uniform prefetch +
// any-lane skip branch around the top-3 insert. Strict < (stable ties).
#define SCAN_STEP(KV, J)                                                    \
    {                                                                       \
        float d = ref_dist(suq, ux, uy, uz, KV.x, KV.y, KV.z, KV.w);        \
        bool c2 = d < d2;                                                   \
        if (__any(c2)) {                                                    \
            int   ti = mbase + t0 + (J);                                    \
            bool  c0 = d < d0, c1 = d < d1;                                 \
            int   n0  = c0 ? ti : i0;                                       \
            int   in0 = c0 ? i0 : ti;                                       \
            int   n1  = c1 ? in0 : i1;                                      \
            int   in1 = c1 ? i1 : ti;                                       \
            int   n2  = c2 ? in1 : i2;                                      \
            float m0 = fminf(d, d0);                                        \
            float m1 = __builtin_amdgcn_fmed3f(d, d0, d1);                  \
            float m2 = __builtin_amdgcn_fmed3f(d, d1, d2);                  \
            d0 = m0; d1 = m1; d2 = m2; i0 = n0; i1 = n1; i2 = n2;           \
        }                                                                   \
    }

__launch_bounds__(256)
__global__ void k_scan_v6(const float* __restrict__ pts,
                          const float4* __restrict__ pk2, const float4* __restrict__ pk3,
                          const float4* __restrict__ pk4,
                          const float* __restrict__ su,
                          float* __restrict__ nd, int* __restrict__ ni) {
    int tid  = blockIdx.x * 256 + threadIdx.x;
    int job  = __builtin_amdgcn_readfirstlane(tid >> 6);   // wave-uniform -> SGPR
    int lane = threadIdx.x & 63;

    int qtile = job / NLS;          // scalar (magic-mul)
    int ls    = job - qtile * NLS;  // scalar: 0..27
    int b     = qtile >> 7;         // 128 qtiles per batch -> scalar
    int q     = (qtile << 6) + lane;

    float ux = pts[q * 3 + 0], uy = pts[q * 3 + 1], uz = pts[q * 3 + 2];
    float suq = su[q];

    const float4* kp; int mbase;
    if (ls < 16)      { mbase = ls << 9;         kp = pk2 + (size_t)b * M2 + mbase; }
    else if (ls < 24) { mbase = (ls - 16) << 9;  kp = pk3 + (size_t)b * M3 + mbase; }
    else              { mbase = (ls - 24) << 9;  kp = pk4 + (size_t)b * M4 + mbase; }

    float d0 = 3e38f, d1 = 3e38f, d2 = 3e38f;
    int   i0 = mbase, i1 = mbase, i2 = mbase;

    for (int t0 = 0; t0 < SEG; t0 += 8) {
        float4 kv0 = kp[t0 + 0], kv1 = kp[t0 + 1], kv2 = kp[t0 + 2], kv3 = kp[t0 + 3];
        float4 kv4 = kp[t0 + 4], kv5 = kp[t0 + 5], kv6 = kp[t0 + 6], kv7 = kp[t0 + 7];
        SCAN_STEP(kv0, 0); SCAN_STEP(kv1, 1); SCAN_STEP(kv2, 2); SCAN_STEP(kv3, 3);
        SCAN_STEP(kv4, 4); SCAN_STEP(kv5, 5); SCAN_STEP(kv6, 6); SCAN_STEP(kv7, 7);
    }
    int base = job * 192 + lane;         // [job][k][lane] -> coalesced
    nd[base]       = d0;  ni[base]       = i0;
    nd[base + 64]  = d1;  ni[base + 64]  = i1;
    nd[base + 128] = d2;  ni[base + 128] = i2;
}

// ---------------------------------------------------------------- kernel 3
// Merge: one thread per (query, level). Segments ascending -> stable ties.
template <int NSEG>
__device__ __forceinline__ double merge_level(int qtile, int lane, int ls0,
                                              const float* __restrict__ nd,
                                              const int* __restrict__ ni,
                                              const float* __restrict__ g) {
    float d0 = 3e38f, d1 = 3e38f, d2 = 3e38f;
    int   i0 = 0, i1 = 0, i2 = 0;
#pragma unroll
    for (int s = 0; s < NSEG; ++s) {
        int jb = ((qtile * NLS) + ls0 + s) * 192 + lane;
#pragma unroll
        for (int k = 0; k < 3; ++k) {
            float d  = nd[jb + k * 64];
            int  idx = ni[jb + k * 64];
            if (d < d2) {
                if (d < d1) {
                    d2 = d1; i2 = i1;
                    if (d < d0) { d1 = d0; i1 = i0; d0 = d; i0 = idx; }
                    else        { d1 = d;  i1 = idx; }
                } else { d2 = d; i2 = idx; }
            }
        }
    }
    // referee weights, bit-exact fp32: r=1/(d+1e-8); w=r/((r0+r1)+r2)
    float r0 = __fdiv_rn(1.0f, __fadd_rn(d0, 1e-8f));
    float r1 = __fdiv_rn(1.0f, __fadd_rn(d1, 1e-8f));
    float r2 = __fdiv_rn(1.0f, __fadd_rn(d2, 1e-8f));
    float s  = __fadd_rn(__fadd_rn(r0, r1), r2);
    float w0 = __fdiv_rn(r0, s), w1 = __fdiv_rn(r1, s), w2 = __fdiv_rn(r2, s);
    return (double)w0 * (double)g[i0] + (double)w1 * (double)g[i1]
         + (double)w2 * (double)g[i2];
}

__global__ void k_merge_v6(const float* __restrict__ nd, const int* __restrict__ ni,
                           const float* __restrict__ g2, const float* __restrict__ g3,
                           const float* __restrict__ g4,
                           double* __restrict__ part) {
    int lvl = blockIdx.x >> 6;                       // 64 blocks per level
    int q   = ((blockIdx.x & 63) << 8) + threadIdx.x;
    int qtile = q >> 6, lane = q & 63;
    int b = q >> 13;

    double v;
    if (lvl == 0)      v = merge_level<16>(qtile, lane, 0,  nd, ni, g2 + b * M2);
    else if (lvl == 1) v = merge_level<8>(qtile, lane, 16, nd, ni, g3 + b * M3);
    else               v = merge_level<4>(qtile, lane, 24, nd, ni, g4 + b * M4);
    part[lvl * NQ + q] = v;
}

// ---------------------------------------------------------------- kernel 4
__global__ void k_sum_v6(const double* __restrict__ part, float* __restrict__ out) {
    int q = blockIdx.x * 256 + threadIdx.x;
    out[q] = (float)(part[q] + part[NQ + q] + part[2 * NQ + q]);
}

// ---------------------------------------------------------------- launch
extern "C" void kernel_launch(void* const* d_in, const int* in_sizes, int n_in,
                              void* d_out, int out_size, void* d_ws, size_t ws_size,
                              hipStream_t stream) {
    const float* pts   = (const float*)d_in[0];
    const float* xyz2  = (const float*)d_in[1];
    const float* feat2 = (const float*)d_in[2];
    const float* xyz3  = (const float*)d_in[3];
    const float* feat3 = (const float*)d_in[4];
    const float* xyz4  = (const float*)d_in[5];
    const float* feat4 = (const float*)d_in[6];
    const float* w_fc  = (const float*)d_in[7];
    const float* w_cls = (const float*)d_in[8];
    float* out = (float*)d_out;

    // workspace layout (same footprint as R5, ~11.6 MB)
    float*  wc  = (float*)d_ws;            // 320
    float*  g2  = wc + 320;                // 16384
    float*  g3  = g2 + 16384;              // 8192
    float*  g4  = g3 + 8192;               // 4096
    float*  su  = g4 + 4096;               // 16384   (float ofs 28992)
    float4* pk2 = (float4*)(su + 16384);   // 16384 float4 (float ofs 45376, 16B aligned)
    float4* pk3 = pk2 + B_ * M2;           // 8192 float4
    float4* pk4 = pk3 + B_ * M3;           // 4096 float4
    float*  nd  = (float*)(pk4 + B_ * M4); // NJOBS*192 floats
    int*    ni  = (int*)(nd + NJOBS * 192);
    // part[3*NQ] doubles ALIAS su..pk3 (dead after k_scan): 393216B <= 458752B
    double* part = (double*)(d_ws);        // recompute precise offset below
    part = (double*)((char*)d_ws + (size_t)28992 * 4);  // = su start, 8B aligned

    k_wc_v6<<<2, 256, 0, stream>>>(w_fc, w_cls, wc);
    k_front_v6<<<FRONT_BLOCKS, 256, 0, stream>>>(
        w_fc, w_cls, pts, xyz2, xyz3, xyz4, feat2, feat3, feat4,
        wc, su, pk2, pk3, pk4, g2, g3, g4);
    k_scan_v6<<<NJOBS / 4, 256, 0, stream>>>(pts, pk2, pk3, pk4, su, nd, ni);
    k_merge_v6<<<192, 256, 0, stream>>>(nd, ni, g2, g3, g4, part);
    k_sum_v6<<<64, 256, 0, stream>>>(part, out);
}

// Round 7
// 112.024 us; speedup vs baseline: 1.7192x; 1.0757x over previous
//
#include <hip/hip_runtime.h>

// Problem constants (from setup_inputs)
#define B_     2
#define NQ     16384     // B*N
#define M2     8192
#define M3     4096
#define M4     2048
#define SEG    512       // known-points per segment job (pass B)
#define NLS    28        // 16 + 8 + 4 segment-jobs per query
#define NQT    256       // query tiles of 64 lanes
#define NJOBS  (NQT*NLS) // 7168 waves (pass B)
#define NLA    14        // pass-A jobs per qtile (8+4+2), 256 cands each
#define NJOBSA (NQT*NLA) // 3584 waves (pass A)

#define GDOT_BLOCKS 7168                        // 28672 waves, one per known point
#define PREP_THREADS (320 + NQ + B_*(M2+M3+M4)) // 45376
#define PREP_BLOCKS 178
#define FRONT_BLOCKS (GDOT_BLOCKS + PREP_BLOCKS)

// Referee model (jax/XLA, verified R4): d = (su - 2*p) + sk, left-to-right fp32.
// su/sk: elementwise square + sequential reduce, NO FMA.
// p: K=3 GEMM ascending-k FMA chain: fma(u2,k2,fma(u1,k1,u0*k0)).
// fl(2p) is exact (pow2 scale), so fmaf(-2,p,su) == fsub(su, fmul(2,p)).
__device__ __forceinline__ float np_sqnorm(float x, float y, float z) {
    return __fadd_rn(__fadd_rn(__fmul_rn(x, x), __fmul_rn(y, y)), __fmul_rn(z, z));
}
__device__ __forceinline__ float ref_dist(float su, float ux, float uy, float uz,
                                          float kx, float ky, float kz, float sk) {
    float p = fmaf(uz, kz, fmaf(uy, ky, __fmul_rn(ux, kx)));
    return __fadd_rn(fmaf(-2.0f, p, su), sk);
}

// ---------------------------------------------------------------- kernel 1
// Fused front: gdot (blocks [0,7168)) + prep (blocks [7168,7346)).
__global__ void k_front_v7(const float* __restrict__ w_fc, const float* __restrict__ w_cls,
                           const float* __restrict__ pts,
                           const float* __restrict__ xyz2, const float* __restrict__ xyz3,
                           const float* __restrict__ xyz4,
                           const float* __restrict__ f2, const float* __restrict__ f3,
                           const float* __restrict__ f4,
                           float* __restrict__ wc, float* __restrict__ su,
                           float4* __restrict__ pk2, float4* __restrict__ pk3,
                           float4* __restrict__ pk4,
                           float* __restrict__ g2, float* __restrict__ g3,
                           float* __restrict__ g4) {
    if (blockIdx.x < GDOT_BLOCKS) {
        // g_lvl[b,m] = feat_lvl[b,m,:] . wc_slice  (one wave per known point)
        int gid  = blockIdx.x * 256 + threadIdx.x;
        int w    = gid >> 6;
        int lane = gid & 63;
        float v;
        if (w < 16384) {                         // level2: C=64, wc[0:64)
            v = f2[(size_t)w * 64 + lane] * wc[lane];
        } else if (w < 24576) {                  // level3: C=128, wc[64:192)
            size_t base = (size_t)(w - 16384) * 128;
            v = fmaf(f3[base + 64 + lane], wc[128 + lane], f3[base + lane] * wc[64 + lane]);
        } else {                                 // level4: C=128, wc[192:320)
            size_t base = (size_t)(w - 24576) * 128;
            v = fmaf(f4[base + 64 + lane], wc[256 + lane], f4[base + lane] * wc[192 + lane]);
        }
        for (int off = 32; off; off >>= 1) v += __shfl_down(v, off, 64);
        if (lane == 0) {
            if (w < 16384) g2[w] = v;
            else if (w < 24576) g3[w - 16384] = v;
            else g4[w - 24576] = v;
        }
        return;
    }
    // prep role: su for queries; packed [kx,ky,kz,sk] per known point
    int i = (blockIdx.x - GDOT_BLOCKS) * 256 + threadIdx.x;
    if (i < 320) return;   // wc handled by k_wc_v7 (must precede gdot readers)
    int j = i - 320;
    if (j < NQ) {
        const float* p = pts + (size_t)j * 3;
        su[j] = np_sqnorm(p[0], p[1], p[2]);
        return;
    }
    j -= NQ;
    if (j < B_ * M2) {
        const float* p = xyz2 + (size_t)j * 3;
        pk2[j] = make_float4(p[0], p[1], p[2], np_sqnorm(p[0], p[1], p[2]));
        return;
    }
    j -= B_ * M2;
    if (j < B_ * M3) {
        const float* p = xyz3 + (size_t)j * 3;
        pk3[j] = make_float4(p[0], p[1], p[2], np_sqnorm(p[0], p[1], p[2]));
        return;
    }
    j -= B_ * M3;
    if (j < B_ * M4) {
        const float* p = xyz4 + (size_t)j * 3;
        pk4[j] = make_float4(p[0], p[1], p[2], np_sqnorm(p[0], p[1], p[2]));
        return;
    }
}

__global__ void k_wc_v7(const float* __restrict__ w_fc, const float* __restrict__ w_cls,
                        float* __restrict__ wc) {
    int c = blockIdx.x * 256 + threadIdx.x;
    if (c < 320) {
        float acc = 0.f;
#pragma unroll
        for (int j = 0; j < 64; ++j) acc = fmaf(w_fc[c * 64 + j], w_cls[j], acc);
        wc[c] = acc;
    }
}

// ---------------------------------------------------------------- kernel 2
// Pass A: values-only top-3 over a QUARTER subset (first 256 of alternating
// 512-segments). 8 VALU/candidate, no cmp/branch/index. Gives certified
// upper bound T >= d3_global per (query, level).
#define STEP_A(KV)                                                          \
    {                                                                       \
        float d = ref_dist(suq, ux, uy, uz, KV.x, KV.y, KV.z, KV.w);        \
        float m1 = __builtin_amdgcn_fmed3f(d, d0, d1);                      \
        float m2 = __builtin_amdgcn_fmed3f(d, d1, d2);                      \
        d0 = fminf(d, d0); d1 = m1; d2 = m2;                                \
    }

__launch_bounds__(256)
__global__ void k_scanA_v7(const float* __restrict__ pts,
                           const float4* __restrict__ pk2, const float4* __restrict__ pk3,
                           const float4* __restrict__ pk4,
                           const float* __restrict__ su,
                           float* __restrict__ ndA) {
    int tid  = blockIdx.x * 256 + threadIdx.x;
    int job  = __builtin_amdgcn_readfirstlane(tid >> 6);
    int lane = threadIdx.x & 63;

    int qtile = job / NLA;          // scalar
    int a     = job - qtile * NLA;  // 0..13
    int b     = qtile >> 7;
    int q     = (qtile << 6) + lane;

    float ux = pts[q * 3 + 0], uy = pts[q * 3 + 1], uz = pts[q * 3 + 2];
    float suq = su[q];

    const float4* kp;
    if (a < 8)       kp = pk2 + (size_t)b * M2 + (a << 10);        // lvl2: 8x256 of 8192
    else if (a < 12) kp = pk3 + (size_t)b * M3 + ((a - 8) << 10);  // lvl3: 4x256 of 4096
    else             kp = pk4 + (size_t)b * M4 + ((a - 12) << 10); // lvl4: 2x256 of 2048

    float d0 = 3e38f, d1 = 3e38f, d2 = 3e38f;
    for (int t0 = 0; t0 < 256; t0 += 8) {
        float4 kv0 = kp[t0 + 0], kv1 = kp[t0 + 1], kv2 = kp[t0 + 2], kv3 = kp[t0 + 3];
        float4 kv4 = kp[t0 + 4], kv5 = kp[t0 + 5], kv6 = kp[t0 + 6], kv7 = kp[t0 + 7];
        STEP_A(kv0); STEP_A(kv1); STEP_A(kv2); STEP_A(kv3);
        STEP_A(kv4); STEP_A(kv5); STEP_A(kv6); STEP_A(kv7);
    }
    int base = job * 192 + lane;
    ndA[base]       = d0;
    ndA[base + 64]  = d1;
    ndA[base + 128] = d2;
}

// ---------------------------------------------------------------- kernel 3
// Pass B: full scan with slots initialized to T+ (next float above T).
// Gate __any(d < d2) now fires only for d <= T (~14% of candidates).
#define SCAN_STEP(KV, J)                                                    \
    {                                                                       \
        float d = ref_dist(suq, ux, uy, uz, KV.x, KV.y, KV.z, KV.w);        \
        bool c2 = d < d2;                                                   \
        if (__any(c2)) {                                                    \
            int   ti = mbase + t0 + (J);                                    \
            bool  c0 = d < d0, c1 = d < d1;                                 \
            int   n0  = c0 ? ti : i0;                                       \
            int   in0 = c0 ? i0 : ti;                                       \
            int   n1  = c1 ? in0 : i1;                                      \
            int   in1 = c1 ? i1 : ti;                                       \
            int   n2  = c2 ? in1 : i2;                                      \
            float m0 = fminf(d, d0);                                        \
            float m1 = __builtin_amdgcn_fmed3f(d, d0, d1);                  \
            float m2 = __builtin_amdgcn_fmed3f(d, d1, d2);                  \
            d0 = m0; d1 = m1; d2 = m2; i0 = n0; i1 = n1; i2 = n2;           \
        }                                                                   \
    }

__launch_bounds__(256)
__global__ void k_scanB_v7(const float* __restrict__ pts,
                           const float4* __restrict__ pk2, const float4* __restrict__ pk3,
                           const float4* __restrict__ pk4,
                           const float* __restrict__ su,
                           const float* __restrict__ ndA,
                           float* __restrict__ nd, int* __restrict__ ni) {
    int tid  = blockIdx.x * 256 + threadIdx.x;
    int job  = __builtin_amdgcn_readfirstlane(tid >> 6);
    int lane = threadIdx.x & 63;

    int qtile = job / NLS;          // scalar
    int ls    = job - qtile * NLS;  // 0..27
    int b     = qtile >> 7;
    int q     = (qtile << 6) + lane;

    float ux = pts[q * 3 + 0], uy = pts[q * 3 + 1], uz = pts[q * 3 + 2];
    float suq = su[q];

    const float4* kp; int mbase, a0, na;
    if (ls < 16)      { mbase = ls << 9;         kp = pk2 + (size_t)b * M2 + mbase; a0 = 0;  na = 8; }
    else if (ls < 24) { mbase = (ls - 16) << 9;  kp = pk3 + (size_t)b * M3 + mbase; a0 = 8;  na = 4; }
    else              { mbase = (ls - 24) << 9;  kp = pk4 + (size_t)b * M4 + mbase; a0 = 12; na = 2; }

    // T = 3rd-min of this level's pass-A triples (certified >= d3_global)
    float t0v = 3e38f, t1v = 3e38f, t2v = 3e38f;
    for (int a = a0; a < a0 + na; ++a) {
        int jb = (qtile * NLA + a) * 192 + lane;
#pragma unroll
        for (int k = 0; k < 3; ++k) {
            float v = ndA[jb + k * 64];
            float m1 = __builtin_amdgcn_fmed3f(v, t0v, t1v);
            float m2 = __builtin_amdgcn_fmed3f(v, t1v, t2v);
            t0v = fminf(v, t0v); t1v = m1; t2v = m2;
        }
    }
    // Tp = next representable float above T (d == T must remain insertable)
    float T = t2v;
    int tb = __float_as_int(T);
    if (T == 0.0f) tb = 1;
    else tb = (T > 0.0f) ? tb + 1 : tb - 1;
    float Tp = __int_as_float(tb);

    float d0 = Tp, d1 = Tp, d2 = Tp;
    int   i0 = mbase, i1 = mbase, i2 = mbase;

    for (int t0 = 0; t0 < SEG; t0 += 8) {
        float4 kv0 = kp[t0 + 0], kv1 = kp[t0 + 1], kv2 = kp[t0 + 2], kv3 = kp[t0 + 3];
        float4 kv4 = kp[t0 + 4], kv5 = kp[t0 + 5], kv6 = kp[t0 + 6], kv7 = kp[t0 + 7];
        SCAN_STEP(kv0, 0); SCAN_STEP(kv1, 1); SCAN_STEP(kv2, 2); SCAN_STEP(kv3, 3);
        SCAN_STEP(kv4, 4); SCAN_STEP(kv5, 5); SCAN_STEP(kv6, 6); SCAN_STEP(kv7, 7);
    }
    int base = job * 192 + lane;         // [job][k][lane] -> coalesced
    nd[base]       = d0;  ni[base]       = i0;
    nd[base + 64]  = d1;  ni[base + 64]  = i1;
    nd[base + 128] = d2;  ni[base + 128] = i2;
}

// ---------------------------------------------------------------- kernel 4
// Merge: one thread per (query, level). Segments ascending -> stable ties.
// Tp-padded slots lose every strict-< comparison to the >=3 real candidates.
template <int NSEG>
__device__ __forceinline__ double merge_level(int qtile, int lane, int ls0,
                                              const float* __restrict__ nd,
                                              const int* __restrict__ ni,
                                              const float* __restrict__ g) {
    float d0 = 3e38f, d1 = 3e38f, d2 = 3e38f;
    int   i0 = 0, i1 = 0, i2 = 0;
#pragma unroll
    for (int s = 0; s < NSEG; ++s) {
        int jb = ((qtile * NLS) + ls0 + s) * 192 + lane;
#pragma unroll
        for (int k = 0; k < 3; ++k) {
            float d  = nd[jb + k * 64];
            int  idx = ni[jb + k * 64];
            if (d < d2) {
                if (d < d1) {
                    d2 = d1; i2 = i1;
                    if (d < d0) { d1 = d0; i1 = i0; d0 = d; i0 = idx; }
                    else        { d1 = d;  i1 = idx; }
                } else { d2 = d; i2 = idx; }
            }
        }
    }
    // referee weights, bit-exact fp32: r=1/(d+1e-8); w=r/((r0+r1)+r2)
    float r0 = __fdiv_rn(1.0f, __fadd_rn(d0, 1e-8f));
    float r1 = __fdiv_rn(1.0f, __fadd_rn(d1, 1e-8f));
    float r2 = __fdiv_rn(1.0f, __fadd_rn(d2, 1e-8f));
    float s  = __fadd_rn(__fadd_rn(r0, r1), r2);
    float w0 = __fdiv_rn(r0, s), w1 = __fdiv_rn(r1, s), w2 = __fdiv_rn(r2, s);
    return (double)w0 * (double)g[i0] + (double)w1 * (double)g[i1]
         + (double)w2 * (double)g[i2];
}

__global__ void k_merge_v7(const float* __restrict__ nd, const int* __restrict__ ni,
                           const float* __restrict__ g2, const float* __restrict__ g3,
                           const float* __restrict__ g4,
                           double* __restrict__ part) {
    int lvl = blockIdx.x >> 6;                       // 64 blocks per level
    int q   = ((blockIdx.x & 63) << 8) + threadIdx.x;
    int qtile = q >> 6, lane = q & 63;
    int b = q >> 13;

    double v;
    if (lvl == 0)      v = merge_level<16>(qtile, lane, 0,  nd, ni, g2 + b * M2);
    else if (lvl == 1) v = merge_level<8>(qtile, lane, 16, nd, ni, g3 + b * M3);
    else               v = merge_level<4>(qtile, lane, 24, nd, ni, g4 + b * M4);
    part[lvl * NQ + q] = v;
}

// ---------------------------------------------------------------- kernel 5
__global__ void k_sum_v7(const double* __restrict__ part, float* __restrict__ out) {
    int q = blockIdx.x * 256 + threadIdx.x;
    out[q] = (float)(part[q] + part[NQ + q] + part[2 * NQ + q]);
}

// ---------------------------------------------------------------- launch
extern "C" void kernel_launch(void* const* d_in, const int* in_sizes, int n_in,
                              void* d_out, int out_size, void* d_ws, size_t ws_size,
                              hipStream_t stream) {
    const float* pts   = (const float*)d_in[0];
    const float* xyz2  = (const float*)d_in[1];
    const float* feat2 = (const float*)d_in[2];
    const float* xyz3  = (const float*)d_in[3];
    const float* feat3 = (const float*)d_in[4];
    const float* xyz4  = (const float*)d_in[5];
    const float* feat4 = (const float*)d_in[6];
    const float* w_fc  = (const float*)d_in[7];
    const float* w_cls = (const float*)d_in[8];
    float* out = (float*)d_out;

    // workspace layout, ~14.4 MB
    float*  wc  = (float*)d_ws;             // 320
    float*  g2  = wc + 320;                 // 16384
    float*  g3  = g2 + 16384;               // 8192
    float*  g4  = g3 + 8192;                // 4096
    float*  su  = g4 + 4096;                // 16384  (float ofs 28992)
    float4* pk2 = (float4*)(su + 16384);    // 16384 float4 (float ofs 45376, 16B aligned)
    float4* pk3 = pk2 + B_ * M2;            // 8192 float4
    float4* pk4 = pk3 + B_ * M3;            // 4096 float4
    float*  ndA = (float*)(pk4 + B_ * M4);  // NJOBSA*192 = 688128 floats
    float*  nd  = ndA + NJOBSA * 192;       // NJOBS*192 = 1376256 floats
    int*    ni  = (int*)(nd + NJOBS * 192); // 1376256 ints
    // part[3*NQ] doubles alias su..pk3 (dead after scanB): 393216 B
    double* part = (double*)((char*)d_ws + (size_t)28992 * 4);

    k_wc_v7<<<2, 256, 0, stream>>>(w_fc, w_cls, wc);
    k_front_v7<<<FRONT_BLOCKS, 256, 0, stream>>>(
        w_fc, w_cls, pts, xyz2, xyz3, xyz4, feat2, feat3, feat4,
        wc, su, pk2, pk3, pk4, g2, g3, g4);
    k_scanA_v7<<<NJOBSA / 4, 256, 0, stream>>>(pts, pk2, pk3, pk4, su, ndA);
    k_scanB_v7<<<NJOBS / 4, 256, 0, stream>>>(pts, pk2, pk3, pk4, su, ndA, nd, ni);
    k_merge_v7<<<192, 256, 0, stream>>>(nd, ni, g2, g3, g4, part);
    k_sum_v7<<<64, 256, 0, stream>>>(part, out);
}